// Round 1
// baseline (908.443 us; speedup 1.0000x reference)
//
#include <hip/hip_runtime.h>
#include <math.h>

#define BB 8
#define NN 1024
#define MM 256
#define BETA 8
#define M1 16
#define NFEAT 64
#define HH 128
#define NTOT 1088   /* N + NGHOST */
#define RMINf 0.5f
#define SPANf 5.5f
#define PIf 3.14159265358979323846f

#define OUT_EI 8
#define OUT_FORCE 8200          /* 8 + 8192 */
#define OUT_VIR 34312           /* 8200 + 8*1088*3 */

/* workspace float offsets */
#define WS_S 0
#define WS_DF (8192*64)
#define WS_STATS (2*8192*64)
#define WS_MUSTD (WS_STATS+4)

__global__ __launch_bounds__(256) void k_feat(
    const float* __restrict__ rvec, const int* __restrict__ tmap,
    const float* __restrict__ c_param, float* __restrict__ S_ws,
    float* __restrict__ stats)
{
  __shared__ float c_lds[256];
  __shared__ float g_lds[256*16];
  __shared__ float q_lds[256*4];
  __shared__ float part[4*64];
  __shared__ float S_lds[64];
  const int bn = blockIdx.x;
  const int n = bn & (NN-1);
  const int tid = threadIdx.x;
  const int ti = tmap[n];
  c_lds[tid] = c_param[ti*256 + tid];

  const int m = tid;
  const float* rp = rvec + ((size_t)bn*MM + m)*3;
  const float x = rp[0], y = rp[1], z = rp[2];
  const float r = sqrtf(x*x + y*y + z*z);
  const float inv_r = 1.0f / r;
  float u = 2.0f*(r - RMINf)/SPANf - 1.0f;
  u = fminf(fmaxf(u, -1.0f), 1.0f);
  const float fc = 0.5f*(cosf(PIf*(r - RMINf)/SPANf) + 1.0f);
  float T[BETA];
  T[0] = 1.0f; T[1] = u;
  for (int k = 2; k < BETA; ++k) T[k] = 2.0f*u*T[k-1] - T[k-2];
  const int tj = m >> 7;
  __syncthreads(); /* c_lds ready */
  const float* cb = &c_lds[tj*128];
  for (int p = 0; p < M1; ++p) {
    const float* cp = cb + p*8;
    float P = 0.f;
    for (int k = 0; k < BETA; ++k) P += cp[k]*T[k];
    g_lds[m*16 + p] = fc * P;
  }
  q_lds[m*4+0] = 1.0f;
  q_lds[m*4+1] = x*inv_r;
  q_lds[m*4+2] = y*inv_r;
  q_lds[m*4+3] = z*inv_r;
  __syncthreads();
  {
    const int pa = tid & 63, chunk = tid >> 6;
    const int p = pa >> 2, a = pa & 3;
    float s = 0.f;
    const int m0 = chunk*64;
    for (int mm = 0; mm < 64; ++mm)
      s += g_lds[(m0+mm)*16 + p] * q_lds[(m0+mm)*4 + a];
    part[chunk*64 + pa] = s;
  }
  __syncthreads();
  if (tid < 64) {
    float s = (part[tid] + part[64+tid] + part[128+tid] + part[192+tid]) * (1.0f/(float)MM);
    S_lds[tid] = s;
    S_ws[(size_t)bn*64 + tid] = s;
  }
  __syncthreads();
  if (tid < 64) {
    const int p = tid >> 2, q = tid & 3;
    float f = 0.f;
    for (int a = 0; a < 4; ++a) f += S_lds[p*4+a]*S_lds[q*4+a];
    float fs = f, fss = f*f;
    for (int o = 32; o > 0; o >>= 1) { fs += __shfl_down(fs, o); fss += __shfl_down(fss, o); }
    if (tid == 0) { atomicAdd(&stats[ti*2+0], fs); atomicAdd(&stats[ti*2+1], fss); }
  }
}

__global__ __launch_bounds__(1024) void k_stats(
    const int* __restrict__ tmap, const float* __restrict__ stats,
    float* __restrict__ mu_std)
{
  __shared__ int wcnt[16];
  const int tid = threadIdx.x;
  const int is0 = (tmap[tid] == 0) ? 1 : 0;
  const unsigned long long bal = __ballot(is0);
  if ((tid & 63) == 0) wcnt[tid >> 6] = (int)__popcll(bal);
  __syncthreads();
  if (tid == 0) {
    int c0 = 0;
    for (int i = 0; i < 16; ++i) c0 += wcnt[i];
    for (int t = 0; t < 2; ++t) {
      const int cn = (t == 0) ? c0 : (NN - c0);
      const float cnt = (float)cn * (float)BB * (float)NFEAT;
      const float mu = stats[t*2+0] / cnt;
      const float var = (stats[t*2+1] - cnt*mu*mu) / (cnt - 1.0f);
      mu_std[t*2+0] = mu;
      mu_std[t*2+1] = sqrtf(fmaxf(var, 1e-20f));
    }
  }
}

__global__ __launch_bounds__(128) void k_mlp(
    const float* __restrict__ S_ws, const int* __restrict__ tmap,
    const float* __restrict__ mu_std,
    const float* __restrict__ W0, const float* __restrict__ b0,
    const float* __restrict__ W1, const float* __restrict__ b1,
    const float* __restrict__ W2, const float* __restrict__ b2,
    const float* __restrict__ Wout, const float* __restrict__ bout,
    float* __restrict__ dfeat_ws, float* __restrict__ out)
{
  __shared__ float S_lds[64];
  __shared__ float x_lds[64];
  __shared__ float h_lds[128];
  __shared__ float dz_lds[128];
  __shared__ float esum[2];
  const int bn = blockIdx.x;
  const int b = bn >> 10;
  const int tid = threadIdx.x;
  const int t = tmap[bn & (NN-1)];
  if (tid < 64) S_lds[tid] = S_ws[(size_t)bn*64 + tid];
  __syncthreads();
  const float mu = mu_std[t*2+0], sd = mu_std[t*2+1];
  if (tid < 64) {
    const int p = tid >> 2, q = tid & 3;
    float f = 0.f;
    for (int a = 0; a < 4; ++a) f += S_lds[p*4+a]*S_lds[q*4+a];
    x_lds[tid] = (f - mu) / sd;
  }
  __syncthreads();
  const float* W0t = W0 + t*NFEAT*HH;
  const float* W1t = W1 + t*HH*HH;
  const float* W2t = W2 + t*HH*HH;
  float z0 = b0[t*HH + tid];
  for (int f = 0; f < NFEAT; ++f) z0 += x_lds[f]*W0t[f*HH + tid];
  const float t0 = tanhf(z0);
  h_lds[tid] = t0;
  __syncthreads();
  float z1 = b1[t*HH + tid];
  for (int f = 0; f < HH; ++f) z1 += h_lds[f]*W1t[f*HH + tid];
  const float t1 = tanhf(z1);
  const float h1 = t1 + t0;
  __syncthreads();
  h_lds[tid] = h1;
  __syncthreads();
  float z2 = b2[t*HH + tid];
  for (int f = 0; f < HH; ++f) z2 += h_lds[f]*W2t[f*HH + tid];
  const float t2 = tanhf(z2);
  const float h2 = t2 + h1;
  const float wo = Wout[t*HH + tid];
  float v = h2 * wo;
  for (int o = 32; o > 0; o >>= 1) v += __shfl_down(v, o);
  if ((tid & 63) == 0) esum[tid >> 6] = v;
  __syncthreads();
  if (tid == 0) {
    const float e = esum[0] + esum[1] + bout[t];
    out[OUT_EI + bn] = e;
    atomicAdd(&out[b], e);
  }
  /* backward */
  const float dh2 = wo;
  const float dz2 = dh2 * (1.0f - t2*t2);
  dz_lds[tid] = dz2;
  __syncthreads();
  float dh1 = dh2;
  for (int h = 0; h < HH; ++h) dh1 += dz_lds[h]*W2t[tid*HH + h];
  const float dz1 = dh1 * (1.0f - t1*t1);
  __syncthreads();
  dz_lds[tid] = dz1;
  __syncthreads();
  float dh0 = dh1;
  for (int h = 0; h < HH; ++h) dh0 += dz_lds[h]*W1t[tid*HH + h];
  const float dz0 = dh0 * (1.0f - t0*t0);
  __syncthreads();
  dz_lds[tid] = dz0;
  __syncthreads();
  if (tid < 64) {
    float dx = 0.f;
    for (int h = 0; h < HH; ++h) dx += dz_lds[h]*W0t[tid*HH + h];
    dfeat_ws[(size_t)bn*64 + tid] = dx / sd;
  }
}

__global__ __launch_bounds__(256) void k_bwd(
    const float* __restrict__ rvec, const int* __restrict__ nlist,
    const int* __restrict__ tmap, const float* __restrict__ c_param,
    const float* __restrict__ S_ws, const float* __restrict__ dfeat_ws,
    float* __restrict__ out)
{
  __shared__ float c_lds[256];
  __shared__ float S_lds[64];
  __shared__ float df_lds[64];
  __shared__ float dS[64];
  __shared__ float wred[4*12];
  const int bn = blockIdx.x;
  const int b = bn >> 10;
  const int n = bn & (NN-1);
  const int tid = threadIdx.x;
  const int ti = tmap[n];
  c_lds[tid] = c_param[ti*256 + tid];
  if (tid < 64) {
    S_lds[tid] = S_ws[(size_t)bn*64 + tid];
    df_lds[tid] = dfeat_ws[(size_t)bn*64 + tid];
  }
  __syncthreads();
  if (tid < 64) {
    const int i = tid >> 2, a = tid & 3;
    float v = 0.f;
    for (int q = 0; q < 4; ++q) v += df_lds[i*4+q]*S_lds[q*4+a];
    if (i < 4)
      for (int p = 0; p < 16; ++p) v += df_lds[p*4+i]*S_lds[p*4+a];
    dS[tid] = v;
  }
  __syncthreads();
  const int m = tid;
  const float* rp = rvec + ((size_t)bn*MM + m)*3;
  const float x = rp[0], y = rp[1], z = rp[2];
  const float r = sqrtf(x*x+y*y+z*z);
  const float inv_r = 1.0f/r;
  const float ux = x*inv_r, uy = y*inv_r, uz = z*inv_r;
  float u = 2.0f*(r - RMINf)/SPANf - 1.0f;
  u = fminf(fmaxf(u, -1.0f), 1.0f);
  const float arg = PIf*(r - RMINf)/SPANf;
  const float fc = 0.5f*(cosf(arg) + 1.0f);
  const float dfc = -0.5f*(PIf/SPANf)*sinf(arg);
  float T[BETA], dT[BETA];
  T[0]=1.f; T[1]=u; dT[0]=0.f; dT[1]=1.f;
  for (int k=2;k<BETA;++k){
    T[k]  = 2.f*u*T[k-1] - T[k-2];
    dT[k] = 2.f*T[k-1] + 2.f*u*dT[k-1] - dT[k-2];
  }
  const int tj = m >> 7;
  const float* cb = &c_lds[tj*128];
  const float dudr = 2.0f/SPANf;
  float A=0.f, dq1=0.f, dq2=0.f, dq3=0.f;
  for (int p=0;p<M1;++p){
    const float* cp = cb + p*8;
    float P=0.f, dP=0.f;
    for (int k=0;k<BETA;++k){ P += cp[k]*T[k]; dP += cp[k]*dT[k]; }
    const float g = fc*P;
    const float dgdr = dfc*P + fc*dP*dudr;
    const float s0=dS[p*4+0], s1=dS[p*4+1], s2=dS[p*4+2], s3=dS[p*4+3];
    const float dgbar = s0 + s1*ux + s2*uy + s3*uz;
    A += dgbar*dgdr;
    dq1 += s1*g; dq2 += s2*g; dq3 += s3*g;
  }
  const float invM = 1.0f/(float)MM;
  A *= invM; dq1 *= invM; dq2 *= invM; dq3 *= invM;
  const float dqu = dq1*ux + dq2*uy + dq3*uz;
  const float d0 = A*ux + (dq1 - dqu*ux)*inv_r;
  const float d1 = A*uy + (dq2 - dqu*uy)*inv_r;
  const float d2 = A*uz + (dq3 - dqu*uz)*inv_r;
  float* Fb = out + OUT_FORCE + (size_t)b*NTOT*3;
  const int nl = nlist[(size_t)bn*MM + m];
  if (nl > 0) {
    const int j = nl - 1;
    atomicAdd(&Fb[j*3+0], -d0);
    atomicAdd(&Fb[j*3+1], -d1);
    atomicAdd(&Fb[j*3+2], -d2);
  }
  float red[12];
  red[0]=d0;    red[1]=d1;    red[2]=d2;
  red[3]=-x*d0; red[4]=-x*d1; red[5]=-x*d2;
  red[6]=-y*d0; red[7]=-y*d1; red[8]=-y*d2;
  red[9]=-z*d0; red[10]=-z*d1; red[11]=-z*d2;
  for (int i=0;i<12;++i){
    float v = red[i];
    for (int o=32;o>0;o>>=1) v += __shfl_down(v,o);
    if ((tid & 63) == 0) wred[(tid>>6)*12 + i] = v;
  }
  __syncthreads();
  if (tid < 12) {
    const float v = wred[tid] + wred[12+tid] + wred[24+tid] + wred[36+tid];
    if (tid < 3) atomicAdd(&Fb[n*3+tid], v);
    else atomicAdd(&out[OUT_VIR + b*9 + (tid-3)], v);
  }
}

extern "C" void kernel_launch(void* const* d_in, const int* in_sizes, int n_in,
                              void* d_out, int out_size, void* d_ws, size_t ws_size,
                              hipStream_t stream)
{
  const int*   nlist = (const int*)d_in[0];
  const int*   tmap  = (const int*)d_in[1];
  const float* rvec  = (const float*)d_in[2];
  const float* cpar  = (const float*)d_in[3];
  const float* W0 = (const float*)d_in[4];
  const float* b0 = (const float*)d_in[5];
  const float* W1 = (const float*)d_in[6];
  const float* b1 = (const float*)d_in[7];
  const float* W2 = (const float*)d_in[8];
  const float* b2 = (const float*)d_in[9];
  const float* Wout = (const float*)d_in[10];
  const float* bout = (const float*)d_in[11];
  float* out = (float*)d_out;
  float* ws = (float*)d_ws;
  float* S_ws   = ws + WS_S;
  float* df_ws  = ws + WS_DF;
  float* stats  = ws + WS_STATS;
  float* mu_std = ws + WS_MUSTD;

  hipMemsetAsync(d_out, 0, (size_t)out_size*sizeof(float), stream);
  hipMemsetAsync(stats, 0, 4*sizeof(float), stream);

  k_feat <<<BB*NN, 256, 0, stream>>>(rvec, tmap, cpar, S_ws, stats);
  k_stats<<<1, 1024, 0, stream>>>(tmap, stats, mu_std);
  k_mlp  <<<BB*NN, 128, 0, stream>>>(S_ws, tmap, mu_std,
                                     W0,b0,W1,b1,W2,b2,Wout,bout, df_ws, out);
  k_bwd  <<<BB*NN, 256, 0, stream>>>(rvec, nlist, tmap, cpar, S_ws, df_ws, out);
}

// Round 2
// 368.653 us; speedup vs baseline: 2.4642x; 2.4642x over previous
//
#include <hip/hip_runtime.h>
#include <math.h>

#define BB 8
#define NN 1024
#define MM 256
#define BETA 8
#define M1 16
#define NFEAT 64
#define HH 128
#define NTOT 1088   /* N + NGHOST */
#define F3 (NTOT*3) /* 3264 */
#define RMINf 0.5f
#define SPANf 5.5f
#define PIf 3.14159265358979323846f

#define OUT_EI 8
#define OUT_FORCE 8200          /* 8 + 8192 */
#define OUT_VIR 34312           /* 8200 + 8*1088*3 */

#define NGROUP 32               /* scatter groups per batch */
#define PAIRS_PER_BATCH (NN*MM) /* 262144 */
#define PAIRS_PER_GROUP (PAIRS_PER_BATCH/NGROUP) /* 8192 */

/* workspace float offsets */
#define WS_S     0
#define WS_DF    (WS_S + 8192*64)
#define WS_DX    (WS_DF + 8192*64)
#define WS_DY    (WS_DX + 8192*256)
#define WS_DZ    (WS_DY + 8192*256)
#define WS_STATP (WS_DZ + 8192*256)      /* 8192*2 */
#define WS_MUSTD (WS_STATP + 8192*2)     /* 4 */
#define WS_VIRP  (WS_MUSTD + 4)          /* 8192*9 */
#define WS_FPART (WS_VIRP + 8192*9)      /* 8*32*3264 = 835584 */
#define WS_WT    (WS_FPART + BB*NGROUP*F3) /* 81920 */
#define WT0_OFF  0
#define WT1_OFF  16384
#define WT2_OFF  49152

__global__ __launch_bounds__(256) void k_transpose(
    const float* __restrict__ W0, const float* __restrict__ W1,
    const float* __restrict__ W2, float* __restrict__ wt)
{
  const int idx = blockIdx.x*256 + threadIdx.x;
  if (idx < 16384) {
    const int t = idx >> 13, rem = idx & 8191;
    const int j = rem >> 6, f = rem & 63;
    wt[WT0_OFF + idx] = W0[t*8192 + f*128 + j];
  } else if (idx < 49152) {
    const int i = idx - 16384;
    const int t = i >> 14, rem = i & 16383;
    const int j = rem >> 7, f = rem & 127;
    wt[WT1_OFF + i] = W1[t*16384 + f*128 + j];
  } else if (idx < 81920) {
    const int i = idx - 49152;
    const int t = i >> 14, rem = i & 16383;
    const int j = rem >> 7, f = rem & 127;
    wt[WT2_OFF + i] = W2[t*16384 + f*128 + j];
  }
}

__global__ __launch_bounds__(256) void k_feat(
    const float* __restrict__ rvec, const int* __restrict__ tmap,
    const float* __restrict__ c_param, float* __restrict__ S_ws,
    float* __restrict__ statp)
{
  __shared__ float c_lds[256];
  __shared__ float g_lds[256*16];
  __shared__ float q_lds[256*4];
  __shared__ float part[4*64];
  __shared__ float S_lds[64];
  const int bn = blockIdx.x;
  const int n = bn & (NN-1);
  const int tid = threadIdx.x;
  const int ti = tmap[n];
  c_lds[tid] = c_param[ti*256 + tid];

  const int m = tid;
  const float* rp = rvec + ((size_t)bn*MM + m)*3;
  const float x = rp[0], y = rp[1], z = rp[2];
  const float r = sqrtf(x*x + y*y + z*z);
  const float inv_r = 1.0f / r;
  float u = 2.0f*(r - RMINf)/SPANf - 1.0f;
  u = fminf(fmaxf(u, -1.0f), 1.0f);
  const float fc = 0.5f*(cosf(PIf*(r - RMINf)/SPANf) + 1.0f);
  float T[BETA];
  T[0] = 1.0f; T[1] = u;
  for (int k = 2; k < BETA; ++k) T[k] = 2.0f*u*T[k-1] - T[k-2];
  const int tj = m >> 7;
  __syncthreads(); /* c_lds ready */
  const float* cb = &c_lds[tj*128];
  for (int p = 0; p < M1; ++p) {
    const float* cp = cb + p*8;
    float P = 0.f;
    for (int k = 0; k < BETA; ++k) P += cp[k]*T[k];
    g_lds[m*16 + p] = fc * P;
  }
  q_lds[m*4+0] = 1.0f;
  q_lds[m*4+1] = x*inv_r;
  q_lds[m*4+2] = y*inv_r;
  q_lds[m*4+3] = z*inv_r;
  __syncthreads();
  {
    const int pa = tid & 63, chunk = tid >> 6;
    const int p = pa >> 2, a = pa & 3;
    float s = 0.f;
    const int m0 = chunk*64;
    for (int mm = 0; mm < 64; ++mm)
      s += g_lds[(m0+mm)*16 + p] * q_lds[(m0+mm)*4 + a];
    part[chunk*64 + pa] = s;
  }
  __syncthreads();
  if (tid < 64) {
    float s = (part[tid] + part[64+tid] + part[128+tid] + part[192+tid]) * (1.0f/(float)MM);
    S_lds[tid] = s;
    S_ws[(size_t)bn*64 + tid] = s;
  }
  __syncthreads();
  if (tid < 64) {
    const int p = tid >> 2, q = tid & 3;
    float f = 0.f;
    for (int a = 0; a < 4; ++a) f += S_lds[p*4+a]*S_lds[q*4+a];
    float fs = f, fss = f*f;
    for (int o = 32; o > 0; o >>= 1) { fs += __shfl_down(fs, o); fss += __shfl_down(fss, o); }
    if (tid == 0) { statp[bn*2+0] = fs; statp[bn*2+1] = fss; }
  }
}

__global__ __launch_bounds__(1024) void k_stats(
    const int* __restrict__ tmap, const float* __restrict__ statp,
    float* __restrict__ mu_std)
{
  __shared__ float wred[16*5];
  const int tid = threadIdx.x;
  const int ti = tmap[tid];
  float fs = 0.f, fss = 0.f;
  for (int b = 0; b < BB; ++b) {
    fs  += statp[(b*NN + tid)*2 + 0];
    fss += statp[(b*NN + tid)*2 + 1];
  }
  float v[5];
  v[0] = (ti == 0) ? fs  : 0.f;
  v[1] = (ti == 0) ? fss : 0.f;
  v[2] = (ti == 1) ? fs  : 0.f;
  v[3] = (ti == 1) ? fss : 0.f;
  v[4] = (ti == 0) ? 1.f : 0.f;
  for (int o = 32; o > 0; o >>= 1)
    for (int i = 0; i < 5; ++i) v[i] += __shfl_down(v[i], o);
  if ((tid & 63) == 0)
    for (int i = 0; i < 5; ++i) wred[(tid >> 6)*5 + i] = v[i];
  __syncthreads();
  if (tid == 0) {
    float s[5] = {0,0,0,0,0};
    for (int w = 0; w < 16; ++w)
      for (int i = 0; i < 5; ++i) s[i] += wred[w*5 + i];
    const float c0 = s[4];
    for (int t = 0; t < 2; ++t) {
      const float cn = (t == 0) ? c0 : ((float)NN - c0);
      const float cnt = cn * (float)BB * (float)NFEAT;
      const float mu = s[t*2+0] / cnt;
      const float var = (s[t*2+1] - cnt*mu*mu) / (cnt - 1.0f);
      mu_std[t*2+0] = mu;
      mu_std[t*2+1] = sqrtf(fmaxf(var, 1e-20f));
    }
  }
}

__global__ __launch_bounds__(128) void k_mlp(
    const float* __restrict__ S_ws, const int* __restrict__ tmap,
    const float* __restrict__ mu_std, const float* __restrict__ wt,
    const float* __restrict__ W0, const float* __restrict__ b0,
    const float* __restrict__ W1, const float* __restrict__ b1,
    const float* __restrict__ W2, const float* __restrict__ b2,
    const float* __restrict__ Wout, const float* __restrict__ bout,
    float* __restrict__ dfeat_ws, float* __restrict__ out)
{
  __shared__ float S_lds[64];
  __shared__ float x_lds[64];
  __shared__ float h_lds[128];
  __shared__ float dz_lds[128];
  __shared__ float esum[2];
  const int bn = blockIdx.x;
  const int b = bn >> 10;
  const int tid = threadIdx.x;
  const int t = tmap[bn & (NN-1)];
  if (tid < 64) S_lds[tid] = S_ws[(size_t)bn*64 + tid];
  __syncthreads();
  const float mu = mu_std[t*2+0], sd = mu_std[t*2+1];
  if (tid < 64) {
    const int p = tid >> 2, q = tid & 3;
    float f = 0.f;
    for (int a = 0; a < 4; ++a) f += S_lds[p*4+a]*S_lds[q*4+a];
    x_lds[tid] = (f - mu) / sd;
  }
  __syncthreads();
  const float* W0t = W0 + t*NFEAT*HH;
  const float* W1t = W1 + t*HH*HH;
  const float* W2t = W2 + t*HH*HH;
  const float* WT0t = wt + WT0_OFF + t*NFEAT*HH;
  const float* WT1t = wt + WT1_OFF + t*HH*HH;
  const float* WT2t = wt + WT2_OFF + t*HH*HH;
  float z0 = b0[t*HH + tid];
  for (int f = 0; f < NFEAT; ++f) z0 += x_lds[f]*W0t[f*HH + tid];
  const float t0 = tanhf(z0);
  h_lds[tid] = t0;
  __syncthreads();
  float z1 = b1[t*HH + tid];
  for (int f = 0; f < HH; ++f) z1 += h_lds[f]*W1t[f*HH + tid];
  const float t1 = tanhf(z1);
  const float h1 = t1 + t0;
  __syncthreads();
  h_lds[tid] = h1;
  __syncthreads();
  float z2 = b2[t*HH + tid];
  for (int f = 0; f < HH; ++f) z2 += h_lds[f]*W2t[f*HH + tid];
  const float t2 = tanhf(z2);
  const float h2 = t2 + h1;
  const float wo = Wout[t*HH + tid];
  float v = h2 * wo;
  for (int o = 32; o > 0; o >>= 1) v += __shfl_down(v, o);
  if ((tid & 63) == 0) esum[tid >> 6] = v;
  __syncthreads();
  if (tid == 0) {
    const float e = esum[0] + esum[1] + bout[t];
    out[OUT_EI + bn] = e;
    atomicAdd(&out[b], e);
  }
  /* backward (coalesced via transposed weights) */
  const float dh2 = wo;
  const float dz2 = dh2 * (1.0f - t2*t2);
  dz_lds[tid] = dz2;
  __syncthreads();
  float dh1 = dh2;
  for (int j = 0; j < HH; ++j) dh1 += dz_lds[j]*WT2t[j*HH + tid];
  const float dz1 = dh1 * (1.0f - t1*t1);
  __syncthreads();
  dz_lds[tid] = dz1;
  __syncthreads();
  float dh0 = dh1;
  for (int j = 0; j < HH; ++j) dh0 += dz_lds[j]*WT1t[j*HH + tid];
  const float dz0 = dh0 * (1.0f - t0*t0);
  __syncthreads();
  dz_lds[tid] = dz0;
  __syncthreads();
  if (tid < 64) {
    float dx = 0.f;
    for (int j = 0; j < HH; ++j) dx += dz_lds[j]*WT0t[j*NFEAT + tid];
    dfeat_ws[(size_t)bn*64 + tid] = dx / sd;
  }
}

__global__ __launch_bounds__(256) void k_bwd(
    const float* __restrict__ rvec,
    const int* __restrict__ tmap, const float* __restrict__ c_param,
    const float* __restrict__ S_ws, const float* __restrict__ dfeat_ws,
    float* __restrict__ dxp, float* __restrict__ dyp, float* __restrict__ dzp,
    float* __restrict__ virp, float* __restrict__ out)
{
  __shared__ float c_lds[256];
  __shared__ float S_lds[64];
  __shared__ float df_lds[64];
  __shared__ float dS[64];
  __shared__ float wred[4*12];
  const int bn = blockIdx.x;
  const int b = bn >> 10;
  const int n = bn & (NN-1);
  const int tid = threadIdx.x;
  const int ti = tmap[n];
  c_lds[tid] = c_param[ti*256 + tid];
  if (tid < 64) {
    S_lds[tid] = S_ws[(size_t)bn*64 + tid];
    df_lds[tid] = dfeat_ws[(size_t)bn*64 + tid];
  }
  __syncthreads();
  if (tid < 64) {
    const int i = tid >> 2, a = tid & 3;
    float v = 0.f;
    for (int q = 0; q < 4; ++q) v += df_lds[i*4+q]*S_lds[q*4+a];
    if (i < 4)
      for (int p = 0; p < 16; ++p) v += df_lds[p*4+i]*S_lds[p*4+a];
    dS[tid] = v;
  }
  __syncthreads();
  const int m = tid;
  const float* rp = rvec + ((size_t)bn*MM + m)*3;
  const float x = rp[0], y = rp[1], z = rp[2];
  const float r = sqrtf(x*x+y*y+z*z);
  const float inv_r = 1.0f/r;
  const float ux = x*inv_r, uy = y*inv_r, uz = z*inv_r;
  float u = 2.0f*(r - RMINf)/SPANf - 1.0f;
  u = fminf(fmaxf(u, -1.0f), 1.0f);
  const float arg = PIf*(r - RMINf)/SPANf;
  const float fc = 0.5f*(cosf(arg) + 1.0f);
  const float dfc = -0.5f*(PIf/SPANf)*sinf(arg);
  float T[BETA], dT[BETA];
  T[0]=1.f; T[1]=u; dT[0]=0.f; dT[1]=1.f;
  for (int k=2;k<BETA;++k){
    T[k]  = 2.f*u*T[k-1] - T[k-2];
    dT[k] = 2.f*T[k-1] + 2.f*u*dT[k-1] - dT[k-2];
  }
  const int tj = m >> 7;
  const float* cb = &c_lds[tj*128];
  const float dudr = 2.0f/SPANf;
  float A=0.f, dq1=0.f, dq2=0.f, dq3=0.f;
  for (int p=0;p<M1;++p){
    const float* cp = cb + p*8;
    float P=0.f, dP=0.f;
    for (int k=0;k<BETA;++k){ P += cp[k]*T[k]; dP += cp[k]*dT[k]; }
    const float g = fc*P;
    const float dgdr = dfc*P + fc*dP*dudr;
    const float s0=dS[p*4+0], s1=dS[p*4+1], s2=dS[p*4+2], s3=dS[p*4+3];
    const float dgbar = s0 + s1*ux + s2*uy + s3*uz;
    A += dgbar*dgdr;
    dq1 += s1*g; dq2 += s2*g; dq3 += s3*g;
  }
  const float invM = 1.0f/(float)MM;
  A *= invM; dq1 *= invM; dq2 *= invM; dq3 *= invM;
  const float dqu = dq1*ux + dq2*uy + dq3*uz;
  const float d0 = A*ux + (dq1 - dqu*ux)*inv_r;
  const float d1 = A*uy + (dq2 - dqu*uy)*inv_r;
  const float d2 = A*uz + (dq3 - dqu*uz)*inv_r;
  const size_t gp = (size_t)bn*MM + m;
  dxp[gp] = d0; dyp[gp] = d1; dzp[gp] = d2;
  float red[12];
  red[0]=d0;    red[1]=d1;    red[2]=d2;
  red[3]=-x*d0; red[4]=-x*d1; red[5]=-x*d2;
  red[6]=-y*d0; red[7]=-y*d1; red[8]=-y*d2;
  red[9]=-z*d0; red[10]=-z*d1; red[11]=-z*d2;
  for (int i=0;i<12;++i){
    float v = red[i];
    for (int o=32;o>0;o>>=1) v += __shfl_down(v,o);
    if ((tid & 63) == 0) wred[(tid>>6)*12 + i] = v;
  }
  __syncthreads();
  if (tid < 12) {
    const float v = wred[tid] + wred[12+tid] + wred[24+tid] + wred[36+tid];
    if (tid < 3) out[OUT_FORCE + (size_t)b*F3 + n*3 + tid] = v;   /* center force, unique */
    else virp[(size_t)bn*9 + (tid-3)] = v;                        /* virial partial */
  }
}

__global__ __launch_bounds__(256) void k_scatter(
    const int* __restrict__ nlist,
    const float* __restrict__ dxp, const float* __restrict__ dyp,
    const float* __restrict__ dzp, float* __restrict__ fpart_ws)
{
  __shared__ float fpart[F3];
  const int tid = threadIdx.x;
  const int blk = blockIdx.x;           /* b*NGROUP + g */
  const int b = blk >> 5;
  const int g = blk & (NGROUP-1);
  for (int i = tid; i < F3; i += 256) fpart[i] = 0.f;
  __syncthreads();
  const size_t base = (size_t)b*PAIRS_PER_BATCH + (size_t)g*PAIRS_PER_GROUP;
  for (int i = 0; i < PAIRS_PER_GROUP/256; ++i) {
    const size_t gp = base + i*256 + tid;
    const int nl = nlist[gp];
    if (nl > 0) {
      const int j = nl - 1;
      atomicAdd(&fpart[j*3+0], -dxp[gp]);
      atomicAdd(&fpart[j*3+1], -dyp[gp]);
      atomicAdd(&fpart[j*3+2], -dzp[gp]);
    }
  }
  __syncthreads();
  float* dst = fpart_ws + (size_t)blk*F3;
  for (int i = tid; i < F3; i += 256) dst[i] = fpart[i];
}

__global__ __launch_bounds__(256) void k_reduce(
    const float* __restrict__ fpart_ws, const float* __restrict__ virp,
    float* __restrict__ out)
{
  const int tid = threadIdx.x;
  if (blockIdx.x == 102) {
    if (tid < 72) {
      const int b = tid / 9, v = tid % 9;
      float s = 0.f;
      for (int n = 0; n < NN; ++n) s += virp[((size_t)b*NN + n)*9 + v];
      out[OUT_VIR + tid] = s;
    }
    return;
  }
  const int e = blockIdx.x*256 + tid;
  if (e >= BB*F3) return;
  const int b = e / F3;
  const int i = e - b*F3;
  float s = 0.f;
  for (int g = 0; g < NGROUP; ++g)
    s += fpart_ws[((size_t)(b*NGROUP + g))*F3 + i];
  out[OUT_FORCE + e] += s;
}

extern "C" void kernel_launch(void* const* d_in, const int* in_sizes, int n_in,
                              void* d_out, int out_size, void* d_ws, size_t ws_size,
                              hipStream_t stream)
{
  const int*   nlist = (const int*)d_in[0];
  const int*   tmap  = (const int*)d_in[1];
  const float* rvec  = (const float*)d_in[2];
  const float* cpar  = (const float*)d_in[3];
  const float* W0 = (const float*)d_in[4];
  const float* b0 = (const float*)d_in[5];
  const float* W1 = (const float*)d_in[6];
  const float* b1 = (const float*)d_in[7];
  const float* W2 = (const float*)d_in[8];
  const float* b2 = (const float*)d_in[9];
  const float* Wout = (const float*)d_in[10];
  const float* bout = (const float*)d_in[11];
  float* out = (float*)d_out;
  float* ws = (float*)d_ws;
  float* S_ws   = ws + WS_S;
  float* df_ws  = ws + WS_DF;
  float* dxp    = ws + WS_DX;
  float* dyp    = ws + WS_DY;
  float* dzp    = ws + WS_DZ;
  float* statp  = ws + WS_STATP;
  float* mu_std = ws + WS_MUSTD;
  float* virp   = ws + WS_VIRP;
  float* fpartw = ws + WS_FPART;
  float* wt     = ws + WS_WT;

  hipMemsetAsync(d_out, 0, (size_t)out_size*sizeof(float), stream);

  k_transpose<<<320, 256, 0, stream>>>(W0, W1, W2, wt);
  k_feat <<<BB*NN, 256, 0, stream>>>(rvec, tmap, cpar, S_ws, statp);
  k_stats<<<1, 1024, 0, stream>>>(tmap, statp, mu_std);
  k_mlp  <<<BB*NN, 128, 0, stream>>>(S_ws, tmap, mu_std, wt,
                                     W0,b0,W1,b1,W2,b2,Wout,bout, df_ws, out);
  k_bwd  <<<BB*NN, 256, 0, stream>>>(rvec, tmap, cpar, S_ws, df_ws,
                                     dxp, dyp, dzp, virp, out);
  k_scatter<<<BB*NGROUP, 256, 0, stream>>>(nlist, dxp, dyp, dzp, fpartw);
  k_reduce <<<103, 256, 0, stream>>>(fpartw, virp, out);
}

// Round 3
// 362.358 us; speedup vs baseline: 2.5070x; 1.0174x over previous
//
#include <hip/hip_runtime.h>
#include <math.h>

#define BB 8
#define NN 1024
#define MM 256
#define BETA 8
#define M1 16
#define NFEAT 64
#define HH 128
#define NTOT 1088   /* N + NGHOST */
#define F3 (NTOT*3) /* 3264 */
#define RMINf 0.5f
#define SPANf 5.5f
#define PIf 3.14159265358979323846f

#define OUT_EI 8
#define OUT_FORCE 8200          /* 8 + 8192 */
#define OUT_VIR 34312           /* 8200 + 8*1088*3 */

#define NGROUP 32               /* scatter groups per batch */
#define PAIRS_PER_BATCH (NN*MM) /* 262144 */
#define PAIRS_PER_GROUP (PAIRS_PER_BATCH/NGROUP) /* 8192 */

#define MT 32                   /* atoms per MLP tile */

/* workspace float offsets */
#define WS_S     0
#define WS_DF    (WS_S + 8192*64)
#define WS_DX    (WS_DF + 8192*64)
#define WS_DY    (WS_DX + 8192*256)
#define WS_DZ    (WS_DY + 8192*256)
#define WS_STATP (WS_DZ + 8192*256)      /* 8192*2 */
#define WS_MUSTD (WS_STATP + 8192*2)     /* 4 */
#define WS_VIRP  (WS_MUSTD + 4)          /* 8192*9 */
#define WS_FPART (WS_VIRP + 8192*9)      /* 8*32*3264 */
#define WS_WT    (WS_FPART + BB*NGROUP*F3) /* 81920 */
#define WT0_OFF  0
#define WT1_OFF  16384
#define WT2_OFF  49152

__global__ __launch_bounds__(256) void k_transpose(
    const float* __restrict__ W0, const float* __restrict__ W1,
    const float* __restrict__ W2, float* __restrict__ wt)
{
  const int idx = blockIdx.x*256 + threadIdx.x;
  if (idx < 16384) {
    const int t = idx >> 13, rem = idx & 8191;
    const int j = rem >> 6, f = rem & 63;
    wt[WT0_OFF + idx] = W0[t*8192 + f*128 + j];
  } else if (idx < 49152) {
    const int i = idx - 16384;
    const int t = i >> 14, rem = i & 16383;
    const int j = rem >> 7, f = rem & 127;
    wt[WT1_OFF + i] = W1[t*16384 + f*128 + j];
  } else if (idx < 81920) {
    const int i = idx - 49152;
    const int t = i >> 14, rem = i & 16383;
    const int j = rem >> 7, f = rem & 127;
    wt[WT2_OFF + i] = W2[t*16384 + f*128 + j];
  }
}

/* ---- features via U-factorization: S[p][a] = (1/M) sum_tj sum_k c[tj][p][k] U[tj][k][a] ---- */
__global__ __launch_bounds__(256) void k_feat(
    const float* __restrict__ rvec, const int* __restrict__ tmap,
    const float* __restrict__ c_param, float* __restrict__ S_ws,
    float* __restrict__ statp)
{
  __shared__ float rv[768];
  __shared__ float c_lds[256];
  __shared__ float prod[256*33];
  __shared__ float part[8*32];
  __shared__ float U[2*32];
  __shared__ float S_lds[64];
  const int bn = blockIdx.x;
  const int n = bn & (NN-1);
  const int tid = threadIdx.x;
  const int ti = tmap[n];
  c_lds[tid] = c_param[ti*256 + tid];
  const float* rb = rvec + (size_t)bn*MM*3;
  rv[tid] = rb[tid]; rv[tid+256] = rb[tid+256]; rv[tid+512] = rb[tid+512];
  __syncthreads();
  const int m = tid;
  const float x = rv[3*m], y = rv[3*m+1], z = rv[3*m+2];
  const float r = sqrtf(x*x + y*y + z*z);
  const float inv_r = 1.0f / r;
  const float ux = x*inv_r, uy = y*inv_r, uz = z*inv_r;
  float u = 2.0f*(r - RMINf)/SPANf - 1.0f;
  u = fminf(fmaxf(u, -1.0f), 1.0f);
  const float fc = 0.5f*(__cosf(PIf*(r - RMINf)/SPANf) + 1.0f);
  float T[BETA];
  T[0] = 1.0f; T[1] = u;
  #pragma unroll
  for (int k = 2; k < BETA; ++k) T[k] = 2.0f*u*T[k-1] - T[k-2];
  float* pr = &prod[m*33];
  #pragma unroll
  for (int k = 0; k < BETA; ++k) {
    const float ft = fc*T[k];
    pr[k*4+0] = ft;
    pr[k*4+1] = ft*ux;
    pr[k*4+2] = ft*uy;
    pr[k*4+3] = ft*uz;
  }
  __syncthreads();
  {
    const int c = tid & 31, oct = tid >> 5;
    const int m0 = oct*32;
    float s = 0.f;
    #pragma unroll 8
    for (int i = 0; i < 32; ++i) s += prod[(m0+i)*33 + c];
    part[oct*32 + c] = s;
  }
  __syncthreads();
  if (tid < 64) {
    const int tj = tid >> 5, c = tid & 31;
    U[tid] = part[(tj*4+0)*32+c] + part[(tj*4+1)*32+c]
           + part[(tj*4+2)*32+c] + part[(tj*4+3)*32+c];
  }
  __syncthreads();
  if (tid < 64) {
    const int p = tid >> 2, a = tid & 3;
    float s = 0.f;
    #pragma unroll
    for (int tj = 0; tj < 2; ++tj)
      #pragma unroll
      for (int k = 0; k < 8; ++k)
        s += c_lds[tj*128 + p*8 + k] * U[tj*32 + k*4 + a];
    s *= (1.0f/(float)MM);
    S_lds[tid] = s;
    S_ws[(size_t)bn*64 + tid] = s;
  }
  __syncthreads();
  if (tid < 64) {
    const int p = tid >> 2, q = tid & 3;
    float f = 0.f;
    #pragma unroll
    for (int a = 0; a < 4; ++a) f += S_lds[p*4+a]*S_lds[q*4+a];
    float fs = f, fss = f*f;
    for (int o = 32; o > 0; o >>= 1) { fs += __shfl_down(fs, o); fss += __shfl_down(fss, o); }
    if (tid == 0) { statp[bn*2+0] = fs; statp[bn*2+1] = fss; }
  }
}

__global__ __launch_bounds__(1024) void k_stats(
    const int* __restrict__ tmap, const float* __restrict__ statp,
    float* __restrict__ mu_std)
{
  __shared__ float wred[16*5];
  const int tid = threadIdx.x;
  const int ti = tmap[tid];
  float fs = 0.f, fss = 0.f;
  for (int b = 0; b < BB; ++b) {
    fs  += statp[(b*NN + tid)*2 + 0];
    fss += statp[(b*NN + tid)*2 + 1];
  }
  float v[5];
  v[0] = (ti == 0) ? fs  : 0.f;
  v[1] = (ti == 0) ? fss : 0.f;
  v[2] = (ti == 1) ? fs  : 0.f;
  v[3] = (ti == 1) ? fss : 0.f;
  v[4] = (ti == 0) ? 1.f : 0.f;
  for (int o = 32; o > 0; o >>= 1)
    for (int i = 0; i < 5; ++i) v[i] += __shfl_down(v[i], o);
  if ((tid & 63) == 0)
    for (int i = 0; i < 5; ++i) wred[(tid >> 6)*5 + i] = v[i];
  __syncthreads();
  if (tid == 0) {
    float s[5] = {0,0,0,0,0};
    for (int w = 0; w < 16; ++w)
      for (int i = 0; i < 5; ++i) s[i] += wred[w*5 + i];
    const float c0 = s[4];
    for (int t = 0; t < 2; ++t) {
      const float cn = (t == 0) ? c0 : ((float)NN - c0);
      const float cnt = cn * (float)BB * (float)NFEAT;
      const float mu = s[t*2+0] / cnt;
      const float var = (s[t*2+1] - cnt*mu*mu) / (cnt - 1.0f);
      mu_std[t*2+0] = mu;
      mu_std[t*2+1] = sqrtf(fmaxf(var, 1e-20f));
    }
  }
}

/* ---- tiled MLP: 32 atoms/block, 4x4 register tile, weights streamed via LDS ---- */
#define GEMM(WPTR, K) \
  for (int kc = 0; kc < (K); kc += 32) { \
    __syncthreads(); \
    { const float4* _s = (const float4*)((WPTR) + kc*128); \
      float4* _d = (float4*)bb; \
      _d[tid] = _s[tid]; _d[tid+256] = _s[tid+256]; \
      _d[tid+512] = _s[tid+512]; _d[tid+768] = _s[tid+768]; } \
    __syncthreads(); \
    _Pragma("unroll") \
    for (int k = 0; k < 32; ++k) { \
      const float4 av = *(const float4*)&aT[(kc+k)*36 + r0]; \
      const float4 bv = *(const float4*)&bb[k*128 + c0]; \
      acc[0][0] += av.x*bv.x; acc[0][1] += av.x*bv.y; acc[0][2] += av.x*bv.z; acc[0][3] += av.x*bv.w; \
      acc[1][0] += av.y*bv.x; acc[1][1] += av.y*bv.y; acc[1][2] += av.y*bv.z; acc[1][3] += av.y*bv.w; \
      acc[2][0] += av.z*bv.x; acc[2][1] += av.z*bv.y; acc[2][2] += av.z*bv.z; acc[2][3] += av.z*bv.w; \
      acc[3][0] += av.w*bv.x; acc[3][1] += av.w*bv.y; acc[3][2] += av.w*bv.z; acc[3][3] += av.w*bv.w; \
    } \
  }

__global__ __launch_bounds__(256) void k_mlp(
    const float* __restrict__ S_ws, const int* __restrict__ tmap,
    const float* __restrict__ mu_std, const float* __restrict__ wt,
    const float* __restrict__ W0, const float* __restrict__ b0,
    const float* __restrict__ W1, const float* __restrict__ b1,
    const float* __restrict__ W2, const float* __restrict__ b2,
    const float* __restrict__ Wout, const float* __restrict__ bout,
    float* __restrict__ dfeat_ws, float* __restrict__ out)
{
  __shared__ float aT[128*36];
  __shared__ float bb[32*128];
  __shared__ float sl[MT*64];
  __shared__ float es[MT];
  const int tb = blockIdx.x;
  const int bn0 = tb*MT;
  const int b = bn0 >> 10;
  const int tid = threadIdx.x;
  const int t = tmap[bn0 & (NN-1)];
  const int rg = tid >> 5, cg = tid & 31;
  const int r0 = rg*4;
  const int c0 = cg*4;
  {
    const float4* src = (const float4*)(S_ws + (size_t)bn0*64);
    ((float4*)sl)[tid] = src[tid];
    ((float4*)sl)[tid+256] = src[tid+256];
  }
  __syncthreads();
  const float mu = mu_std[t*2], sd = mu_std[t*2+1];
  const float inv_sd = 1.0f/sd;
  #pragma unroll
  for (int i = 0; i < 8; ++i) {
    const int e = i*256 + tid;
    const int r = e >> 6, f = e & 63;
    const int p = f >> 2, q = f & 3;
    const float* Sr = &sl[r*64];
    float s = 0.f;
    #pragma unroll
    for (int a = 0; a < 4; ++a) s += Sr[p*4+a]*Sr[q*4+a];
    aT[f*36 + r] = (s - mu)*inv_sd;
  }

  float acc[4][4], t0r[4][4], t1r[4][4], t2r[4][4], dh1r[4][4], wor[4];

  /* L0: z0 = x @ W0 + b0, K=64 */
  {
    const float* bp = b0 + t*HH;
    float bj0 = bp[c0], bj1 = bp[c0+1], bj2 = bp[c0+2], bj3 = bp[c0+3];
    #pragma unroll
    for (int i = 0; i < 4; ++i) { acc[i][0]=bj0; acc[i][1]=bj1; acc[i][2]=bj2; acc[i][3]=bj3; }
  }
  GEMM(W0 + (size_t)t*NFEAT*HH, 64);
  #pragma unroll
  for (int i = 0; i < 4; ++i)
    #pragma unroll
    for (int j = 0; j < 4; ++j) t0r[i][j] = tanhf(acc[i][j]);
  __syncthreads();
  #pragma unroll
  for (int i = 0; i < 4; ++i)
    #pragma unroll
    for (int j = 0; j < 4; ++j) aT[(c0+j)*36 + r0+i] = t0r[i][j];

  /* L1 */
  {
    const float* bp = b1 + t*HH;
    float bj0 = bp[c0], bj1 = bp[c0+1], bj2 = bp[c0+2], bj3 = bp[c0+3];
    #pragma unroll
    for (int i = 0; i < 4; ++i) { acc[i][0]=bj0; acc[i][1]=bj1; acc[i][2]=bj2; acc[i][3]=bj3; }
  }
  GEMM(W1 + (size_t)t*HH*HH, 128);
  #pragma unroll
  for (int i = 0; i < 4; ++i)
    #pragma unroll
    for (int j = 0; j < 4; ++j) t1r[i][j] = tanhf(acc[i][j]);
  __syncthreads();
  #pragma unroll
  for (int i = 0; i < 4; ++i)
    #pragma unroll
    for (int j = 0; j < 4; ++j) aT[(c0+j)*36 + r0+i] = t1r[i][j] + t0r[i][j];

  /* L2 */
  {
    const float* bp = b2 + t*HH;
    float bj0 = bp[c0], bj1 = bp[c0+1], bj2 = bp[c0+2], bj3 = bp[c0+3];
    #pragma unroll
    for (int i = 0; i < 4; ++i) { acc[i][0]=bj0; acc[i][1]=bj1; acc[i][2]=bj2; acc[i][3]=bj3; }
  }
  GEMM(W2 + (size_t)t*HH*HH, 128);
  #pragma unroll
  for (int i = 0; i < 4; ++i)
    #pragma unroll
    for (int j = 0; j < 4; ++j) t2r[i][j] = tanhf(acc[i][j]);

  #pragma unroll
  for (int j = 0; j < 4; ++j) wor[j] = Wout[t*HH + c0 + j];

  /* energy */
  {
    float pr[4];
    #pragma unroll
    for (int i = 0; i < 4; ++i) {
      pr[i] = 0.f;
      #pragma unroll
      for (int j = 0; j < 4; ++j)
        pr[i] += (t2r[i][j] + t1r[i][j] + t0r[i][j]) * wor[j];
    }
    for (int o = 16; o > 0; o >>= 1) {
      pr[0] += __shfl_down(pr[0], o, 32);
      pr[1] += __shfl_down(pr[1], o, 32);
      pr[2] += __shfl_down(pr[2], o, 32);
      pr[3] += __shfl_down(pr[3], o, 32);
    }
    if (cg == 0) { es[r0]=pr[0]; es[r0+1]=pr[1]; es[r0+2]=pr[2]; es[r0+3]=pr[3]; }
  }
  __syncthreads();
  if (tid < MT) out[OUT_EI + bn0 + tid] = es[tid] + bout[t];
  if (tid == 0) {
    float s = 0.f;
    for (int i = 0; i < MT; ++i) s += es[i];
    atomicAdd(&out[b], s + (float)MT*bout[t]);
  }

  /* backward: dz2 = wo*(1-t2^2) */
  __syncthreads();
  #pragma unroll
  for (int i = 0; i < 4; ++i)
    #pragma unroll
    for (int j = 0; j < 4; ++j) {
      const float dz2 = wor[j]*(1.0f - t2r[i][j]*t2r[i][j]);
      t2r[i][j] = dz2;
      aT[(c0+j)*36 + r0+i] = dz2;
    }
  /* dh1 = wo + dz2 @ W2^T */
  #pragma unroll
  for (int i = 0; i < 4; ++i)
    #pragma unroll
    for (int j = 0; j < 4; ++j) acc[i][j] = wor[j];
  GEMM(wt + WT2_OFF + (size_t)t*HH*HH, 128);
  #pragma unroll
  for (int i = 0; i < 4; ++i)
    #pragma unroll
    for (int j = 0; j < 4; ++j) dh1r[i][j] = acc[i][j];
  __syncthreads();
  #pragma unroll
  for (int i = 0; i < 4; ++i)
    #pragma unroll
    for (int j = 0; j < 4; ++j) {
      const float dz1 = dh1r[i][j]*(1.0f - t1r[i][j]*t1r[i][j]);
      t1r[i][j] = dz1;
      aT[(c0+j)*36 + r0+i] = dz1;
    }
  /* dh0 = dh1 + dz1 @ W1^T */
  #pragma unroll
  for (int i = 0; i < 4; ++i)
    #pragma unroll
    for (int j = 0; j < 4; ++j) acc[i][j] = dh1r[i][j];
  GEMM(wt + WT1_OFF + (size_t)t*HH*HH, 128);
  __syncthreads();
  #pragma unroll
  for (int i = 0; i < 4; ++i)
    #pragma unroll
    for (int j = 0; j < 4; ++j)
      aT[(c0+j)*36 + r0+i] = acc[i][j]*(1.0f - t0r[i][j]*t0r[i][j]);

  /* dx = dz0 @ W0^T : 32x64 out, tile 4x2 */
  {
    float a2[4][2];
    #pragma unroll
    for (int i = 0; i < 4; ++i) { a2[i][0]=0.f; a2[i][1]=0.f; }
    const float* WT0t = wt + WT0_OFF + (size_t)t*HH*NFEAT;
    for (int kc = 0; kc < 128; kc += 64) {
      __syncthreads();
      { const float4* _s = (const float4*)(WT0t + kc*64);
        float4* _d = (float4*)bb;
        _d[tid] = _s[tid]; _d[tid+256] = _s[tid+256];
        _d[tid+512] = _s[tid+512]; _d[tid+768] = _s[tid+768]; }
      __syncthreads();
      #pragma unroll 16
      for (int k = 0; k < 64; ++k) {
        const float4 av = *(const float4*)&aT[(kc+k)*36 + r0];
        const float2 bv = *(const float2*)&bb[k*64 + cg*2];
        a2[0][0] += av.x*bv.x; a2[0][1] += av.x*bv.y;
        a2[1][0] += av.y*bv.x; a2[1][1] += av.y*bv.y;
        a2[2][0] += av.z*bv.x; a2[2][1] += av.z*bv.y;
        a2[3][0] += av.w*bv.x; a2[3][1] += av.w*bv.y;
      }
    }
    #pragma unroll
    for (int i = 0; i < 4; ++i) {
      float2 v; v.x = a2[i][0]*inv_sd; v.y = a2[i][1]*inv_sd;
      *(float2*)&dfeat_ws[(size_t)(bn0 + r0 + i)*64 + cg*2] = v;
    }
  }
}

/* ---- backward pair kernel via E-factorization ---- */
__global__ __launch_bounds__(256) void k_bwd(
    const float* __restrict__ rvec,
    const int* __restrict__ tmap, const float* __restrict__ c_param,
    const float* __restrict__ S_ws, const float* __restrict__ dfeat_ws,
    float* __restrict__ dxp, float* __restrict__ dyp, float* __restrict__ dzp,
    float* __restrict__ virp, float* __restrict__ out)
{
  __shared__ float rv[768];
  __shared__ float c_lds[256];
  __shared__ float S_lds[64];
  __shared__ float df_lds[64];
  __shared__ float dS[64];
  __shared__ float E[64];
  __shared__ float wred[4*12];
  const int bn = blockIdx.x;
  const int b = bn >> 10;
  const int n = bn & (NN-1);
  const int tid = threadIdx.x;
  const int ti = tmap[n];
  c_lds[tid] = c_param[ti*256 + tid];
  const float* rb = rvec + (size_t)bn*MM*3;
  rv[tid] = rb[tid]; rv[tid+256] = rb[tid+256]; rv[tid+512] = rb[tid+512];
  if (tid < 64) {
    S_lds[tid] = S_ws[(size_t)bn*64 + tid];
    df_lds[tid] = dfeat_ws[(size_t)bn*64 + tid];
  }
  __syncthreads();
  if (tid < 64) {
    const int i = tid >> 2, a = tid & 3;
    float v = 0.f;
    #pragma unroll
    for (int q = 0; q < 4; ++q) v += df_lds[i*4+q]*S_lds[q*4+a];
    if (i < 4)
      for (int p = 0; p < 16; ++p) v += df_lds[p*4+i]*S_lds[p*4+a];
    dS[tid] = v;
  }
  __syncthreads();
  if (tid < 64) {
    const int tj = tid >> 5, rem = tid & 31;
    const int a = rem >> 3, k = rem & 7;
    float e = 0.f;
    #pragma unroll
    for (int p = 0; p < 16; ++p) e += dS[p*4+a]*c_lds[tj*128 + p*8 + k];
    E[tj*32 + a*8 + k] = e;
  }
  __syncthreads();
  const int m = tid;
  const float x = rv[3*m], y = rv[3*m+1], z = rv[3*m+2];
  const float r = sqrtf(x*x+y*y+z*z);
  const float inv_r = 1.0f/r;
  const float ux = x*inv_r, uy = y*inv_r, uz = z*inv_r;
  float u = 2.0f*(r - RMINf)/SPANf - 1.0f;
  u = fminf(fmaxf(u, -1.0f), 1.0f);
  const float arg = PIf*(r - RMINf)/SPANf;
  float sarg, carg;
  __sincosf(arg, &sarg, &carg);
  const float fc = 0.5f*(carg + 1.0f);
  const float dfc = -0.5f*(PIf/SPANf)*sarg;
  float T[BETA], dT[BETA];
  T[0]=1.f; T[1]=u; dT[0]=0.f; dT[1]=1.f;
  #pragma unroll
  for (int k=2;k<BETA;++k){
    T[k]  = 2.f*u*T[k-1] - T[k-2];
    dT[k] = 2.f*T[k-1] + 2.f*u*dT[k-1] - dT[k-2];
  }
  const float* Et = &E[(m >> 7)*32];
  float ta[4], tda[4];
  #pragma unroll
  for (int a = 0; a < 4; ++a) {
    float s = 0.f, sd2 = 0.f;
    #pragma unroll
    for (int k = 0; k < 8; ++k) {
      const float e = Et[a*8 + k];
      s   += T[k]*e;
      sd2 += dT[k]*e;
    }
    ta[a] = s; tda[a] = sd2;
  }
  const float dudr = 2.0f/SPANf;
  const float invM = 1.0f/(float)MM;
  float A = dfc*(ta[0] + ux*ta[1] + uy*ta[2] + uz*ta[3])
          + fc*dudr*(tda[0] + ux*tda[1] + uy*tda[2] + uz*tda[3]);
  float dq1 = fc*ta[1], dq2 = fc*ta[2], dq3 = fc*ta[3];
  A *= invM; dq1 *= invM; dq2 *= invM; dq3 *= invM;
  const float dqu = dq1*ux + dq2*uy + dq3*uz;
  const float d0 = A*ux + (dq1 - dqu*ux)*inv_r;
  const float d1 = A*uy + (dq2 - dqu*uy)*inv_r;
  const float d2 = A*uz + (dq3 - dqu*uz)*inv_r;
  const size_t gp = (size_t)bn*MM + m;
  dxp[gp] = d0; dyp[gp] = d1; dzp[gp] = d2;
  float red[12];
  red[0]=d0;    red[1]=d1;    red[2]=d2;
  red[3]=-x*d0; red[4]=-x*d1; red[5]=-x*d2;
  red[6]=-y*d0; red[7]=-y*d1; red[8]=-y*d2;
  red[9]=-z*d0; red[10]=-z*d1; red[11]=-z*d2;
  #pragma unroll
  for (int i=0;i<12;++i){
    float v = red[i];
    for (int o=32;o>0;o>>=1) v += __shfl_down(v,o);
    if ((tid & 63) == 0) wred[(tid>>6)*12 + i] = v;
  }
  __syncthreads();
  if (tid < 12) {
    const float v = wred[tid] + wred[12+tid] + wred[24+tid] + wred[36+tid];
    if (tid < 3) out[OUT_FORCE + (size_t)b*F3 + n*3 + tid] = v;
    else virp[(size_t)bn*9 + (tid-3)] = v;
  }
}

__global__ __launch_bounds__(256) void k_scatter(
    const int* __restrict__ nlist,
    const float* __restrict__ dxp, const float* __restrict__ dyp,
    const float* __restrict__ dzp, float* __restrict__ fpart_ws)
{
  __shared__ float fpart[F3];
  const int tid = threadIdx.x;
  const int blk = blockIdx.x;
  const int b = blk >> 5;
  const int g = blk & (NGROUP-1);
  for (int i = tid; i < F3; i += 256) fpart[i] = 0.f;
  __syncthreads();
  const size_t base = (size_t)b*PAIRS_PER_BATCH + (size_t)g*PAIRS_PER_GROUP;
  for (int i = 0; i < PAIRS_PER_GROUP/256; ++i) {
    const size_t gp = base + i*256 + tid;
    const int nl = nlist[gp];
    if (nl > 0) {
      const int j = nl - 1;
      atomicAdd(&fpart[j*3+0], -dxp[gp]);
      atomicAdd(&fpart[j*3+1], -dyp[gp]);
      atomicAdd(&fpart[j*3+2], -dzp[gp]);
    }
  }
  __syncthreads();
  float* dst = fpart_ws + (size_t)blk*F3;
  for (int i = tid; i < F3; i += 256) dst[i] = fpart[i];
}

__global__ __launch_bounds__(256) void k_reduce(
    const float* __restrict__ fpart_ws, const float* __restrict__ virp,
    float* __restrict__ out)
{
  const int tid = threadIdx.x;
  if (blockIdx.x == 102) {
    if (tid < 72) {
      const int b = tid / 9, v = tid % 9;
      float s = 0.f;
      for (int n = 0; n < NN; ++n) s += virp[((size_t)b*NN + n)*9 + v];
      out[OUT_VIR + tid] = s;
    }
    return;
  }
  const int e = blockIdx.x*256 + tid;
  if (e >= BB*F3) return;
  const int b = e / F3;
  const int i = e - b*F3;
  float s = 0.f;
  for (int g = 0; g < NGROUP; ++g)
    s += fpart_ws[((size_t)(b*NGROUP + g))*F3 + i];
  out[OUT_FORCE + e] += s;
}

extern "C" void kernel_launch(void* const* d_in, const int* in_sizes, int n_in,
                              void* d_out, int out_size, void* d_ws, size_t ws_size,
                              hipStream_t stream)
{
  const int*   nlist = (const int*)d_in[0];
  const int*   tmap  = (const int*)d_in[1];
  const float* rvec  = (const float*)d_in[2];
  const float* cpar  = (const float*)d_in[3];
  const float* W0 = (const float*)d_in[4];
  const float* b0 = (const float*)d_in[5];
  const float* W1 = (const float*)d_in[6];
  const float* b1 = (const float*)d_in[7];
  const float* W2 = (const float*)d_in[8];
  const float* b2 = (const float*)d_in[9];
  const float* Wout = (const float*)d_in[10];
  const float* bout = (const float*)d_in[11];
  float* out = (float*)d_out;
  float* ws = (float*)d_ws;
  float* S_ws   = ws + WS_S;
  float* df_ws  = ws + WS_DF;
  float* dxp    = ws + WS_DX;
  float* dyp    = ws + WS_DY;
  float* dzp    = ws + WS_DZ;
  float* statp  = ws + WS_STATP;
  float* mu_std = ws + WS_MUSTD;
  float* virp   = ws + WS_VIRP;
  float* fpartw = ws + WS_FPART;
  float* wt     = ws + WS_WT;

  hipMemsetAsync(d_out, 0, (size_t)out_size*sizeof(float), stream);

  k_transpose<<<320, 256, 0, stream>>>(W0, W1, W2, wt);
  k_feat <<<BB*NN, 256, 0, stream>>>(rvec, tmap, cpar, S_ws, statp);
  k_stats<<<1, 1024, 0, stream>>>(tmap, statp, mu_std);
  k_mlp  <<<(BB*NN)/MT, 256, 0, stream>>>(S_ws, tmap, mu_std, wt,
                                     W0,b0,W1,b1,W2,b2,Wout,bout, df_ws, out);
  k_bwd  <<<BB*NN, 256, 0, stream>>>(rvec, tmap, cpar, S_ws, df_ws,
                                     dxp, dyp, dzp, virp, out);
  k_scatter<<<BB*NGROUP, 256, 0, stream>>>(nlist, dxp, dyp, dzp, fpartw);
  k_reduce <<<103, 256, 0, stream>>>(fpartw, virp, out);
}